// Round 1
// baseline (318.328 us; speedup 1.0000x reference)
//
#include <hip/hip_runtime.h>
#include <stdint.h>

// ---------------- problem constants ----------------
#define B    8192
#define D    256
#define C    7
#define NTOT 8199          // B + C
#define NP   8320          // 65 * 128 (padded rows)
#define NTILE 65
#define TEMP_INV 12.5f
#define BETAC 0.005f       // 0.5*(1-GAMMA)
#define L2GAMMA (-0.0144995696951151f)  // log2(0.99)

using short8 = __attribute__((ext_vector_type(8))) short;
using f32x4  = __attribute__((ext_vector_type(4))) float;

// bf16 round-to-nearest-even from f32
__device__ __forceinline__ unsigned short f2bf(float x) {
    unsigned u = __float_as_uint(x);
    unsigned r = (u + 0x7fffu + ((u >> 16) & 1u)) >> 16;
    return (unsigned short)r;
}

__device__ __forceinline__ void async16(const void* src, void* dst) {
    __builtin_amdgcn_global_load_lds(
        (const __attribute__((address_space(1))) void*)src,
        (__attribute__((address_space(3))) void*)dst, 16, 0, 0);
}

// score formula: ((1+sim)*0.5 + 1e-8) * 12.5 = sim*6.25 + (6.25 + 1.25e-7)
__device__ __forceinline__ float score_of(float sim) {
    return fmaf(sim, 6.25f, 6.25f + 1.25e-7f);
}

// ---------------- kernel 1: ranks -> weights, labs_ext, histogram ----------------
__global__ void kprep(const int* __restrict__ labels, float* __restrict__ wbuf,
                      int* __restrict__ labs_ext, int* __restrict__ hist) {
    __shared__ int cnt[256 * 8];
    __shared__ int tot[8];
    int t = threadIdx.x;
    #pragma unroll
    for (int c = 0; c < 8; ++c) cnt[t * 8 + c] = 0;
    __syncthreads();
    // pass 1: per-chunk class counts (each thread owns 32 consecutive labels)
    for (int k = 0; k < 32; ++k) {
        int c = labels[t * 32 + k];
        cnt[t * 8 + c]++;
    }
    __syncthreads();
    // exclusive scan per class (7 threads, serial over 256 chunks — tiny)
    if (t < C) {
        int base = 0;
        for (int u = 0; u < 256; ++u) {
            int tmp = cnt[u * 8 + t];
            cnt[u * 8 + t] = base;
            base += tmp;
        }
        tot[t] = base;
        hist[t] = base;
    }
    __syncthreads();
    // pass 2: rank -> weight = gamma^(n_c - rank)
    for (int k = 0; k < 32; ++k) {
        int idx = t * 32 + k;
        int c = labels[idx];
        int r = ++cnt[t * 8 + c];          // 1-based rank in batch order
        int kk = tot[c] - r;
        wbuf[idx] = exp2f((float)kk * L2GAMMA);
    }
    // extended labels: features, prototypes (0..6), pad (-1)
    for (int i = t; i < NP; i += 256)
        labs_ext[i] = (i < B) ? labels[i] : ((i < NTOT) ? (i - B) : -1);
}

// ---------------- kernel 2: S[c][d] = sum w_i f_i[d], Wsum[c] ----------------
__global__ void kaccum(const float* __restrict__ feats, const int* __restrict__ labels,
                       const float* __restrict__ wbuf, float* __restrict__ S,
                       float* __restrict__ Wsum) {
    __shared__ float acc[C * 256];
    __shared__ float wacc[8];
    int t = threadIdx.x;
    #pragma unroll
    for (int c = 0; c < C; ++c) acc[c * 256 + t] = 0.f;
    if (t < 8) wacc[t] = 0.f;
    __syncthreads();
    int base = blockIdx.x * 64;
    for (int r = 0; r < 64; ++r) {
        int row = base + r;
        int c = labels[row];
        float wv = wbuf[row];
        acc[c * 256 + t] += wv * feats[(size_t)row * 256 + t];
        if (t == 0) wacc[c] += wv;
    }
    __syncthreads();
    #pragma unroll
    for (int c = 0; c < C; ++c) {
        float v = acc[c * 256 + t];
        if (v != 0.f) atomicAdd(&S[c * 256 + t], v);
    }
    if (t < C) {
        float v = wacc[t];
        if (v != 0.f) atomicAdd(&Wsum[t], v);
    }
}

// ---------------- kernel 3: target build + Householder QR + proto G rows ----------------
__global__ void kproto(const float* __restrict__ S, const float* __restrict__ Wsum,
                       const int* __restrict__ hist, const float* __restrict__ protos,
                       const float* __restrict__ moms, unsigned short* __restrict__ G) {
    __shared__ float A[256 * 8];   // A[d][c] = target^T (d row, c col)
    __shared__ float V[256 * 8];   // Householder vectors
    __shared__ float vvs[8];
    __shared__ float bcast[8];
    int t = threadIdx.x;
    int lane = t & 63, w = t >> 6;
    #pragma unroll
    for (int c = 0; c < C; ++c) {
        float p = protos[c * 256 + t];
        float m0 = moms[c * 256 + t];
        float gn = exp2f((float)hist[c] * L2GAMMA);          // gamma^{n_c}
        float mf = gn * m0 + BETAC * (S[c * 256 + t] - Wsum[c] * p);
        A[t * 8 + c] = p + mf;
        V[t * 8 + c] = 0.f;
    }
    __syncthreads();
    // Householder QR (LAPACK sign convention: beta = -sign(alpha)*norm)
    for (int j = 0; j < C; ++j) {
        if (w == 0) {
            float s = 0.f;
            for (int i = lane; i < 256; i += 64) {
                float a = (i >= j) ? A[i * 8 + j] : 0.f;
                s += a * a;
            }
            #pragma unroll
            for (int off = 32; off; off >>= 1) s += __shfl_xor(s, off);
            if (lane == 0) {
                float norm = sqrtf(s);
                float alpha = A[j * 8 + j];
                float beta = (alpha >= 0.f) ? -norm : norm;
                float vv = 2.f * beta * (beta - alpha);
                bcast[0] = alpha; bcast[1] = beta;
                bcast[2] = (vv > 0.f) ? 1.f : 0.f;
                vvs[j] = (vv > 0.f) ? vv : 1.f;
            }
        }
        __syncthreads();
        float alpha = bcast[0], beta = bcast[1], valid = bcast[2];
        float vi = 0.f;
        if (valid != 0.f) {
            if (t == j) vi = alpha - beta;
            else if (t > j) vi = A[t * 8 + j];
        }
        V[t * 8 + j] = vi;
        __syncthreads();
        float vvj = vvs[j];
        for (int k = j + 1 + w; k < C; k += 4) {   // waves split trailing columns
            float cp = 0.f;
            for (int i = lane; i < 256; i += 64) cp += V[i * 8 + j] * A[i * 8 + k];
            #pragma unroll
            for (int off = 32; off; off >>= 1) cp += __shfl_xor(cp, off);
            float scale = 2.f * cp / vvj;
            for (int i = lane; i < 256; i += 64) A[i * 8 + k] -= scale * V[i * 8 + j];
        }
        __syncthreads();
    }
    // form Q = H_1 ... H_7 * E  (reuse A as E)
    #pragma unroll
    for (int c = 0; c < C; ++c) A[t * 8 + c] = (t == c) ? 1.f : 0.f;
    __syncthreads();
    for (int j = C - 1; j >= 0; --j) {
        float vvj = vvs[j];
        for (int k = w; k < C; k += 4) {
            float cp = 0.f;
            for (int i = lane; i < 256; i += 64) cp += V[i * 8 + j] * A[i * 8 + k];
            #pragma unroll
            for (int off = 32; off; off >>= 1) cp += __shfl_xor(cp, off);
            float scale = 2.f * cp / vvj;
            for (int i = lane; i < 256; i += 64) A[i * 8 + k] -= scale * V[i * 8 + j];
        }
        __syncthreads();
    }
    // normalize columns (rows of new prototypes) and emit bf16 G rows 8192..8198
    for (int c = w; c < C; c += 4) {
        float s = 0.f;
        for (int i = lane; i < 256; i += 64) { float a = A[i * 8 + c]; s += a * a; }
        #pragma unroll
        for (int off = 32; off; off >>= 1) s += __shfl_xor(s, off);
        if (lane == 0) bcast[c] = 1.f / sqrtf(s);
    }
    __syncthreads();
    #pragma unroll
    for (int c = 0; c < C; ++c)
        G[(size_t)(B + c) * 256 + t] = f2bf(A[t * 8 + c] * bcast[c]);
    // zero the pad rows 8199..8319
    for (int i = NTOT * 256 + t; i < NP * 256; i += 256) G[i] = 0;
}

// ---------------- kernel 4: normalize features -> bf16 G rows 0..8191 ----------------
__global__ void knorm(const float* __restrict__ feats, unsigned short* __restrict__ G) {
    int w = threadIdx.x >> 6, lane = threadIdx.x & 63;
    int row = blockIdx.x * 4 + w;
    const float4 v = *(const float4*)(feats + (size_t)row * 256 + lane * 4);
    float s = v.x * v.x + v.y * v.y + v.z * v.z + v.w * v.w;
    #pragma unroll
    for (int off = 1; off < 64; off <<= 1) s += __shfl_xor(s, off);
    float rn = 1.f / sqrtf(s);
    ushort4 o;
    o.x = f2bf(v.x * rn); o.y = f2bf(v.y * rn);
    o.z = f2bf(v.z * rn); o.w = f2bf(v.w * rn);
    *(ushort4*)(G + (size_t)row * 256 + lane * 4) = o;
}

// ---------------- kernel 5: fused G G^T -> per-row pos-sum / neg-expsum / max ----------------
__global__ __launch_bounds__(256) void kmain(const unsigned short* __restrict__ G,
                                             const int* __restrict__ labs,
                                             float* __restrict__ possum,
                                             float* __restrict__ negsum,
                                             unsigned* __restrict__ maxb) {
    __shared__ unsigned short Asm[128 * 64];
    __shared__ unsigned short Bsm[128 * 64];
    __shared__ int labI[128], labJ[128];
    int tid = threadIdx.x;
    int it = blockIdx.y, jt = blockIdx.x;
    int rowA = it * 128, rowB = jt * 128;
    if (tid < 128) labI[tid] = labs[rowA + tid];
    else           labJ[tid - 128] = labs[rowB + tid - 128];
    int lane = tid & 63, w = tid >> 6;
    int wr = w >> 1, wc = w & 1;

    f32x4 acc[4][4];
    #pragma unroll
    for (int m = 0; m < 4; ++m)
        #pragma unroll
        for (int n = 0; n < 4; ++n) acc[m][n] = 0.f;

    const char* gb = (const char*)G;
    for (int ks = 0; ks < 4; ++ks) {
        __syncthreads();   // readers of previous tile done (and labI/labJ visible)
        #pragma unroll
        for (int q = 0; q < 4; ++q) {
            int o = q * 4096 + w * 1024 + lane * 16;       // linear LDS byte offset
            int row = o >> 7, colb = o & 127;
            int sc = colb ^ ((row & 7) << 4);              // inverse-swizzled SOURCE
            const char* srcA = gb + (size_t)(rowA + row) * 512 + ks * 128 + sc;
            const char* srcB = gb + (size_t)(rowB + row) * 512 + ks * 128 + sc;
            async16(srcA, (char*)Asm + q * 4096 + w * 1024);
            async16(srcB, (char*)Bsm + q * 4096 + w * 1024);
        }
        asm volatile("s_waitcnt vmcnt(0)" ::: "memory");
        __syncthreads();
        #pragma unroll
        for (int kk = 0; kk < 2; ++kk) {
            short8 af[4], bfr[4];
            #pragma unroll
            for (int m = 0; m < 4; ++m) {
                int r0 = wr * 64 + m * 16 + (lane & 15);
                int cb = (kk * 64 + (lane >> 4) * 16) ^ ((r0 & 7) << 4);  // swizzled read
                af[m] = *(const short8*)((const char*)Asm + r0 * 128 + cb);
            }
            #pragma unroll
            for (int n = 0; n < 4; ++n) {
                int r0 = wc * 64 + n * 16 + (lane & 15);
                int cb = (kk * 64 + (lane >> 4) * 16) ^ ((r0 & 7) << 4);
                bfr[n] = *(const short8*)((const char*)Bsm + r0 * 128 + cb);
            }
            #pragma unroll
            for (int m = 0; m < 4; ++m)
                #pragma unroll
                for (int n = 0; n < 4; ++n)
                    acc[m][n] = __builtin_amdgcn_mfma_f32_16x16x32_bf16(af[m], bfr[n], acc[m][n], 0, 0, 0);
        }
    }

    // fused epilogue: C/D layout col=lane&15, row=(lane>>4)*4+reg
    int g4 = lane >> 4, q15 = lane & 15;
    int ljv[4];
    #pragma unroll
    for (int n = 0; n < 4; ++n) ljv[n] = labJ[wc * 64 + n * 16 + q15];
    float wavemax = -3.f;
    #pragma unroll
    for (int m = 0; m < 4; ++m) {
        #pragma unroll
        for (int r = 0; r < 4; ++r) {
            int il = wr * 64 + m * 16 + g4 * 4 + r;
            int i = rowA + il;
            int li = labI[il];
            float ps = 0.f, ns = 0.f;
            #pragma unroll
            for (int n = 0; n < 4; ++n) {
                int j = rowB + wc * 64 + n * 16 + q15;
                float sim = acc[m][n][r];
                bool valid = (i < NTOT) && (j < NTOT) && (i != j);
                float s = score_of(sim);
                if (valid) {
                    wavemax = fmaxf(wavemax, sim);
                    if (li == ljv[n]) ps += s;
                    else              ns += __expf(s);
                }
            }
            #pragma unroll
            for (int off = 1; off < 16; off <<= 1) {
                ps += __shfl_xor(ps, off);
                ns += __shfl_xor(ns, off);
            }
            if (q15 == 0 && i < NTOT) {
                atomicAdd(&possum[i], ps);
                atomicAdd(&negsum[i], ns);
            }
        }
    }
    #pragma unroll
    for (int off = 1; off < 64; off <<= 1)
        wavemax = fmaxf(wavemax, __shfl_xor(wavemax, off));
    if (lane == 0 && wavemax > 0.f)
        atomicMax(maxb, __float_as_uint(wavemax));   // positive floats: uint order == float order
}

// ---------------- kernel 6: finalize ----------------
__global__ void kfinal(const float* __restrict__ possum, const float* __restrict__ negsum,
                       const unsigned* __restrict__ maxb, const int* __restrict__ hist,
                       const int* __restrict__ labs, float* __restrict__ out) {
    int t = threadIdx.x;
    int lane = t & 63, w = t >> 6;
    float M = score_of(__uint_as_float(maxb[0]));
    float expnM = __expf(-M);
    float lsum = 0.f, lcnt = 0.f;
    for (int i = t; i < NTOT; i += 256) {
        float cnt = (float)hist[labs[i]];
        float pos = (possum[i] - M * cnt) / (cnt + 1e-8f);
        float neg = logf(negsum[i] * expnM + 1e-8f);
        float loss = neg - pos;
        if (loss > 0.f) { lsum += loss; lcnt += 1.f; }
    }
    #pragma unroll
    for (int off = 1; off < 64; off <<= 1) {
        lsum += __shfl_xor(lsum, off);
        lcnt += __shfl_xor(lcnt, off);
    }
    __shared__ float s1[4], s2[4];
    if (lane == 0) { s1[w] = lsum; s2[w] = lcnt; }
    __syncthreads();
    if (t == 0) {
        float a = s1[0] + s1[1] + s1[2] + s1[3];
        float c = s2[0] + s2[1] + s2[2] + s2[3];
        out[0] = (c > 0.f) ? a / fmaxf(c, 1.f) : 0.f;
    }
}

// ---------------- launcher ----------------
extern "C" void kernel_launch(void* const* d_in, const int* in_sizes, int n_in,
                              void* d_out, int out_size, void* d_ws, size_t ws_size,
                              hipStream_t stream) {
    const float* feats  = (const float*)d_in[0];
    const int*   labels = (const int*)d_in[1];
    const float* protos = (const float*)d_in[2];
    const float* moms   = (const float*)d_in[3];
    float* out = (float*)d_out;

    char* ws = (char*)d_ws;
    float*    S_      = (float*)(ws + 0);        // 1792 f32
    float*    Wsum    = (float*)(ws + 7168);     // 8 f32
    int*      hist    = (int*)  (ws + 7200);     // 8 int
    float*    possum  = (float*)(ws + 7424);     // 8320 f32
    float*    negsum  = (float*)(ws + 40704);    // 8320 f32
    unsigned* maxb    = (unsigned*)(ws + 73984); // 1
    float*    wbuf    = (float*)(ws + 74240);    // 8192 f32
    int*      labs    = (int*)  (ws + 107008);   // 8320 int
    unsigned short* G = (unsigned short*)(ws + 140544);  // 8320*256 bf16

    hipMemsetAsync(ws, 0, 74000, stream);   // zero all accumulators (S..maxb)

    kprep<<<1, 256, 0, stream>>>(labels, wbuf, labs, hist);
    kaccum<<<128, 256, 0, stream>>>(feats, labels, wbuf, S_, Wsum);
    kproto<<<1, 256, 0, stream>>>(S_, Wsum, hist, protos, moms, G);
    knorm<<<2048, 256, 0, stream>>>(feats, G);
    kmain<<<dim3(NTILE, NTILE), 256, 0, stream>>>(G, labs, possum, negsum, maxb);
    kfinal<<<1, 256, 0, stream>>>(possum, negsum, maxb, hist, labs, out);
}

// Round 2
// 214.359 us; speedup vs baseline: 1.4850x; 1.4850x over previous
//
#include <hip/hip_runtime.h>
#include <stdint.h>

// ---------------- problem constants ----------------
#define B    8192
#define D    256
#define C    7
#define NTOT 8199          // B + C
#define NP   8320          // 65 * 128 (padded rows)
#define NTILE 65
#define NBLK 2145          // 65*66/2 triangular
#define BETAC 0.005f       // 0.5*(1-GAMMA)
#define L2GAMMA (-0.0144995696951151f)  // log2(0.99)

using short8 = __attribute__((ext_vector_type(8))) short;
using f32x4  = __attribute__((ext_vector_type(4))) float;

// bf16 round-to-nearest-even from f32
__device__ __forceinline__ unsigned short f2bf(float x) {
    unsigned u = __float_as_uint(x);
    unsigned r = (u + 0x7fffu + ((u >> 16) & 1u)) >> 16;
    return (unsigned short)r;
}

__device__ __forceinline__ void async16(const void* src, void* dst) {
    __builtin_amdgcn_global_load_lds(
        (const __attribute__((address_space(1))) void*)src,
        (__attribute__((address_space(3))) void*)dst, 16, 0, 0);
}

// score formula: ((1+sim)*0.5 + 1e-8) * 12.5 = sim*6.25 + (6.25 + 1.25e-7)
__device__ __forceinline__ float score_of(float sim) {
    return fmaf(sim, 6.25f, 6.25f + 1.25e-7f);
}

#define WAITVM(N) asm volatile("s_waitcnt vmcnt(" #N ")" ::: "memory")
#define BARRIER() do { __builtin_amdgcn_s_barrier(); asm volatile("" ::: "memory"); } while(0)

// ---------------- kernel 1: ranks -> weights, labs_ext, histogram ----------------
__global__ void kprep(const int* __restrict__ labels, float* __restrict__ wbuf,
                      int* __restrict__ labs_ext, int* __restrict__ hist) {
    __shared__ int cnt[256 * 8];
    __shared__ int tot[8];
    int t = threadIdx.x;
    #pragma unroll
    for (int c = 0; c < 8; ++c) cnt[t * 8 + c] = 0;
    __syncthreads();
    for (int k = 0; k < 32; ++k) {
        int c = labels[t * 32 + k];
        cnt[t * 8 + c]++;
    }
    __syncthreads();
    if (t < C) {
        int base = 0;
        for (int u = 0; u < 256; ++u) {
            int tmp = cnt[u * 8 + t];
            cnt[u * 8 + t] = base;
            base += tmp;
        }
        tot[t] = base;
        hist[t] = base;
    }
    __syncthreads();
    for (int k = 0; k < 32; ++k) {
        int idx = t * 32 + k;
        int c = labels[idx];
        int r = ++cnt[t * 8 + c];          // 1-based rank in batch order
        int kk = tot[c] - r;
        wbuf[idx] = exp2f((float)kk * L2GAMMA);
    }
    for (int i = t; i < NP; i += 256)
        labs_ext[i] = (i < B) ? labels[i] : ((i < NTOT) ? (i - B) : -1);
}

// ---------------- kernel 2: S[c][d] = sum w_i f_i[d], Wsum[c] ----------------
__global__ void kaccum(const float* __restrict__ feats, const int* __restrict__ labels,
                       const float* __restrict__ wbuf, float* __restrict__ S,
                       float* __restrict__ Wsum) {
    __shared__ float acc[C * 256];
    __shared__ float wacc[8];
    int t = threadIdx.x;
    #pragma unroll
    for (int c = 0; c < C; ++c) acc[c * 256 + t] = 0.f;
    if (t < 8) wacc[t] = 0.f;
    __syncthreads();
    int base = blockIdx.x * 64;
    for (int r = 0; r < 64; ++r) {
        int row = base + r;
        int c = labels[row];
        float wv = wbuf[row];
        acc[c * 256 + t] += wv * feats[(size_t)row * 256 + t];
        if (t == 0) wacc[c] += wv;
    }
    __syncthreads();
    #pragma unroll
    for (int c = 0; c < C; ++c) {
        float v = acc[c * 256 + t];
        if (v != 0.f) atomicAdd(&S[c * 256 + t], v);
    }
    if (t < C) {
        float v = wacc[t];
        if (v != 0.f) atomicAdd(&Wsum[t], v);
    }
}

// ---------------- kernel 3: target build + Householder QR + proto G rows ----------------
__global__ void kproto(const float* __restrict__ S, const float* __restrict__ Wsum,
                       const int* __restrict__ hist, const float* __restrict__ protos,
                       const float* __restrict__ moms, unsigned short* __restrict__ G) {
    __shared__ float A[256 * 8];
    __shared__ float V[256 * 8];
    __shared__ float vvs[8];
    __shared__ float bcast[8];
    int t = threadIdx.x;
    int lane = t & 63, w = t >> 6;
    #pragma unroll
    for (int c = 0; c < C; ++c) {
        float p = protos[c * 256 + t];
        float m0 = moms[c * 256 + t];
        float gn = exp2f((float)hist[c] * L2GAMMA);
        float mf = gn * m0 + BETAC * (S[c * 256 + t] - Wsum[c] * p);
        A[t * 8 + c] = p + mf;
        V[t * 8 + c] = 0.f;
    }
    __syncthreads();
    for (int j = 0; j < C; ++j) {
        if (w == 0) {
            float s = 0.f;
            for (int i = lane; i < 256; i += 64) {
                float a = (i >= j) ? A[i * 8 + j] : 0.f;
                s += a * a;
            }
            #pragma unroll
            for (int off = 32; off; off >>= 1) s += __shfl_xor(s, off);
            if (lane == 0) {
                float norm = sqrtf(s);
                float alpha = A[j * 8 + j];
                float beta = (alpha >= 0.f) ? -norm : norm;
                float vv = 2.f * beta * (beta - alpha);
                bcast[0] = alpha; bcast[1] = beta;
                bcast[2] = (vv > 0.f) ? 1.f : 0.f;
                vvs[j] = (vv > 0.f) ? vv : 1.f;
            }
        }
        __syncthreads();
        float alpha = bcast[0], valid = bcast[2];
        float beta = bcast[1];
        float vi = 0.f;
        if (valid != 0.f) {
            if (t == j) vi = alpha - beta;
            else if (t > j) vi = A[t * 8 + j];
        }
        V[t * 8 + j] = vi;
        __syncthreads();
        float vvj = vvs[j];
        for (int k = j + 1 + w; k < C; k += 4) {
            float cp = 0.f;
            for (int i = lane; i < 256; i += 64) cp += V[i * 8 + j] * A[i * 8 + k];
            #pragma unroll
            for (int off = 32; off; off >>= 1) cp += __shfl_xor(cp, off);
            float scale = 2.f * cp / vvj;
            for (int i = lane; i < 256; i += 64) A[i * 8 + k] -= scale * V[i * 8 + j];
        }
        __syncthreads();
    }
    #pragma unroll
    for (int c = 0; c < C; ++c) A[t * 8 + c] = (t == c) ? 1.f : 0.f;
    __syncthreads();
    for (int j = C - 1; j >= 0; --j) {
        float vvj = vvs[j];
        for (int k = w; k < C; k += 4) {
            float cp = 0.f;
            for (int i = lane; i < 256; i += 64) cp += V[i * 8 + j] * A[i * 8 + k];
            #pragma unroll
            for (int off = 32; off; off >>= 1) cp += __shfl_xor(cp, off);
            float scale = 2.f * cp / vvj;
            for (int i = lane; i < 256; i += 64) A[i * 8 + k] -= scale * V[i * 8 + j];
        }
        __syncthreads();
    }
    for (int c = w; c < C; c += 4) {
        float s = 0.f;
        for (int i = lane; i < 256; i += 64) { float a = A[i * 8 + c]; s += a * a; }
        #pragma unroll
        for (int off = 32; off; off >>= 1) s += __shfl_xor(s, off);
        if (lane == 0) bcast[c] = 1.f / sqrtf(s);
    }
    __syncthreads();
    #pragma unroll
    for (int c = 0; c < C; ++c)
        G[(size_t)(B + c) * 256 + t] = f2bf(A[t * 8 + c] * bcast[c]);
    for (int i = NTOT * 256 + t; i < NP * 256; i += 256) G[i] = 0;
}

// ---------------- kernel 4: normalize features -> bf16 G rows 0..8191 ----------------
__global__ void knorm(const float* __restrict__ feats, unsigned short* __restrict__ G) {
    int w = threadIdx.x >> 6, lane = threadIdx.x & 63;
    int row = blockIdx.x * 4 + w;
    const float4 v = *(const float4*)(feats + (size_t)row * 256 + lane * 4);
    float s = v.x * v.x + v.y * v.y + v.z * v.z + v.w * v.w;
    #pragma unroll
    for (int off = 1; off < 64; off <<= 1) s += __shfl_xor(s, off);
    float rn = 1.f / sqrtf(s);
    ushort4 o;
    o.x = f2bf(v.x * rn); o.y = f2bf(v.y * rn);
    o.z = f2bf(v.z * rn); o.w = f2bf(v.w * rn);
    *(ushort4*)(G + (size_t)row * 256 + lane * 4) = o;
}

// ---------------- kernel 5: symmetric fused G G^T, partial-store epilogue ----------------
__global__ __launch_bounds__(256) void kmain(const unsigned short* __restrict__ G,
                                             const int* __restrict__ labs,
                                             float* __restrict__ pP,
                                             float* __restrict__ pN,
                                             unsigned* __restrict__ maxb) {
    __shared__ unsigned short Asm_[4][128][64];   // 4 K-tiles of A (32 KB)
    __shared__ unsigned short Bsm_[4][128][64];   // 4 K-tiles of B (32 KB)
    __shared__ int   labIJ[256];                  // labI | labJ
    __shared__ float rowP[2][128], rowN[2][128];  // cross-wc combine
    __shared__ float colP[2][128], colN[2][128];  // cross-wr combine

    int b = blockIdx.x;
    // triangular decode: pairs (it <= jt)
    int jt = (int)((sqrtf(8.f * (float)b + 1.f) - 1.f) * 0.5f);
    while ((jt * (jt + 1)) / 2 > b) --jt;
    while (((jt + 1) * (jt + 2)) / 2 <= b) ++jt;
    int it = b - (jt * (jt + 1)) / 2;

    int rowA = it * 128, rowB = jt * 128;
    int tid = threadIdx.x, lane = tid & 63, w = tid >> 6;
    int wr = w >> 1, wc = w & 1;

    const char* gb = (const char*)G;
    const char* lb = (const char*)labs;

    // ---- issue ALL staging (counted-vmcnt pipeline). Order per wave:
    // 1 label load, then 8 loads per ks (total 33 outstanding).
    {
        const char* src = (lane < 32) ? (lb + rowA * 4 + lane * 16)
                                      : (lb + rowB * 4 + (lane - 32) * 16);
        async16(src, (char*)labIJ);
    }
    #pragma unroll
    for (int ks = 0; ks < 4; ++ks) {
        #pragma unroll
        for (int q = 0; q < 4; ++q) {
            int o = q * 4096 + w * 1024 + lane * 16;   // linear LDS byte offset in tile
            int row = o >> 7, colb = o & 127;
            int sc = colb ^ ((row & 7) << 4);          // inverse-swizzled SOURCE
            const char* sA = gb + (size_t)(rowA + row) * 512 + ks * 128 + sc;
            const char* sB = gb + (size_t)(rowB + row) * 512 + ks * 128 + sc;
            async16(sA, (char*)Asm_ + ks * 16384 + q * 4096 + w * 1024);
            async16(sB, (char*)Bsm_ + ks * 16384 + q * 4096 + w * 1024);
        }
    }

    f32x4 acc[4][4];
    #pragma unroll
    for (int m = 0; m < 4; ++m)
        #pragma unroll
        for (int n = 0; n < 4; ++n) acc[m][n] = 0.f;

#define KSTEP(KS)                                                              \
    do {                                                                       \
        _Pragma("unroll")                                                      \
        for (int kk = 0; kk < 2; ++kk) {                                       \
            short8 af[4], bfr[4];                                              \
            _Pragma("unroll")                                                  \
            for (int m = 0; m < 4; ++m) {                                      \
                int r0 = wr * 64 + m * 16 + (lane & 15);                       \
                int cb = (kk * 64 + (lane >> 4) * 16) ^ ((r0 & 7) << 4);       \
                af[m] = *(const short8*)((const char*)Asm_ + (KS) * 16384 + r0 * 128 + cb); \
            }                                                                  \
            _Pragma("unroll")                                                  \
            for (int n = 0; n < 4; ++n) {                                      \
                int r0 = wc * 64 + n * 16 + (lane & 15);                       \
                int cb = (kk * 64 + (lane >> 4) * 16) ^ ((r0 & 7) << 4);       \
                bfr[n] = *(const short8*)((const char*)Bsm_ + (KS) * 16384 + r0 * 128 + cb); \
            }                                                                  \
            __builtin_amdgcn_s_setprio(1);                                     \
            _Pragma("unroll")                                                  \
            for (int m = 0; m < 4; ++m)                                        \
                _Pragma("unroll")                                              \
                for (int n = 0; n < 4; ++n)                                    \
                    acc[m][n] = __builtin_amdgcn_mfma_f32_16x16x32_bf16(af[m], bfr[n], acc[m][n], 0, 0, 0); \
            __builtin_amdgcn_s_setprio(0);                                     \
        }                                                                      \
    } while (0)

    WAITVM(24); BARRIER(); KSTEP(0);
    WAITVM(16); BARRIER(); KSTEP(1);
    WAITVM(8);  BARRIER(); KSTEP(2);
    WAITVM(0);  BARRIER(); KSTEP(3);
#undef KSTEP

    // ---- fused epilogue: C/D layout col=lane&15, row=(lane>>4)*4+reg
    int g4 = lane >> 4, q15 = lane & 15;
    const int* labI = labIJ;
    const int* labJ = labIJ + 128;
    int ljv[4];
    #pragma unroll
    for (int n = 0; n < 4; ++n) ljv[n] = labJ[wc * 64 + n * 16 + q15];
    float wavemax = -3.f;
    float cs[4] = {0.f, 0.f, 0.f, 0.f}, cn[4] = {0.f, 0.f, 0.f, 0.f};
    #pragma unroll
    for (int m = 0; m < 4; ++m) {
        #pragma unroll
        for (int r = 0; r < 4; ++r) {
            int il = wr * 64 + m * 16 + g4 * 4 + r;
            int i = rowA + il;
            int li = labI[il];
            float ps = 0.f, ns = 0.f;
            #pragma unroll
            for (int n = 0; n < 4; ++n) {
                int j = rowB + wc * 64 + n * 16 + q15;
                float sim = acc[m][n][r];
                bool valid = (i < NTOT) && (j < NTOT) && (i != j);
                float s = score_of(sim);
                float e = __expf(s);
                if (valid) {
                    wavemax = fmaxf(wavemax, sim);
                    if (li == ljv[n]) { ps += s; cs[n] += s; }
                    else              { ns += e; cn[n] += e; }
                }
            }
            #pragma unroll
            for (int off = 1; off < 16; off <<= 1) {
                ps += __shfl_xor(ps, off);
                ns += __shfl_xor(ns, off);
            }
            if (q15 == 0) { rowP[wc][il] = ps; rowN[wc][il] = ns; }
        }
    }
    // col-side: reduce over g4 groups (same q15, different rows)
    #pragma unroll
    for (int n = 0; n < 4; ++n) {
        float a = cs[n], bb = cn[n];
        a += __shfl_xor(a, 16); a += __shfl_xor(a, 32);
        bb += __shfl_xor(bb, 16); bb += __shfl_xor(bb, 32);
        if (g4 == 0) {
            colP[wr][wc * 64 + n * 16 + q15] = a;
            colN[wr][wc * 64 + n * 16 + q15] = bb;
        }
    }
    #pragma unroll
    for (int off = 1; off < 64; off <<= 1)
        wavemax = fmaxf(wavemax, __shfl_xor(wavemax, off));
    if (lane == 0 && wavemax > 0.f)
        atomicMax(maxb, __float_as_uint(wavemax));

    __syncthreads();
    if (tid < 128) {
        pP[(size_t)jt * NP + rowA + tid] = rowP[0][tid] + rowP[1][tid];
        pN[(size_t)jt * NP + rowA + tid] = rowN[0][tid] + rowN[1][tid];
        if (it != jt) {
            pP[(size_t)it * NP + rowB + tid] = colP[0][tid] + colP[1][tid];
            pN[(size_t)it * NP + rowB + tid] = colN[0][tid] + colN[1][tid];
        }
    }
}

// ---------------- kernel 6: reduce partials -> per-row loss -> masked-mean pieces ----------------
__global__ void kreduce(const float* __restrict__ pP, const float* __restrict__ pN,
                        const unsigned* __restrict__ maxb, const int* __restrict__ hist,
                        const int* __restrict__ labs, float* __restrict__ lossacc) {
    int i = blockIdx.x * 256 + threadIdx.x;
    float lsum = 0.f, lcnt = 0.f;
    if (i < NTOT) {
        float sp = 0.f, sn = 0.f;
        #pragma unroll 5
        for (int c = 0; c < NTILE; ++c) {
            sp += pP[(size_t)c * NP + i];
            sn += pN[(size_t)c * NP + i];
        }
        float M = score_of(__uint_as_float(maxb[0]));
        float cnt = (float)hist[labs[i]];
        float pos = (sp - M * cnt) / (cnt + 1e-8f);
        float neg = logf(sn * __expf(-M) + 1e-8f);
        float loss = neg - pos;
        if (loss > 0.f) { lsum = loss; lcnt = 1.f; }
    }
    #pragma unroll
    for (int off = 1; off < 64; off <<= 1) {
        lsum += __shfl_xor(lsum, off);
        lcnt += __shfl_xor(lcnt, off);
    }
    __shared__ float s1[4], s2[4];
    int lane = threadIdx.x & 63, w = threadIdx.x >> 6;
    if (lane == 0) { s1[w] = lsum; s2[w] = lcnt; }
    __syncthreads();
    if (threadIdx.x == 0) {
        atomicAdd(&lossacc[0], s1[0] + s1[1] + s1[2] + s1[3]);
        atomicAdd(&lossacc[1], s2[0] + s2[1] + s2[2] + s2[3]);
    }
}

__global__ void kfin(const float* __restrict__ lossacc, float* __restrict__ out) {
    if (threadIdx.x == 0) {
        float a = lossacc[0], c = lossacc[1];
        out[0] = (c > 0.f) ? a / fmaxf(c, 1.f) : 0.f;
    }
}

// ---------------- launcher ----------------
extern "C" void kernel_launch(void* const* d_in, const int* in_sizes, int n_in,
                              void* d_out, int out_size, void* d_ws, size_t ws_size,
                              hipStream_t stream) {
    const float* feats  = (const float*)d_in[0];
    const int*   labels = (const int*)d_in[1];
    const float* protos = (const float*)d_in[2];
    const float* moms   = (const float*)d_in[3];
    float* out = (float*)d_out;

    char* ws = (char*)d_ws;
    float*    S_      = (float*)(ws + 0);        // 1792 f32
    float*    Wsum    = (float*)(ws + 7168);     // 8 f32
    int*      hist    = (int*)  (ws + 7200);     // 8 int
    unsigned* maxb    = (unsigned*)(ws + 7232);  // 1
    float*    lossacc = (float*)(ws + 7236);     // 2 f32
    float*    wbuf    = (float*)(ws + 7296);     // 8192 f32 -> 40064
    int*      labs    = (int*)  (ws + 40064);    // 8320 int -> 73344
    unsigned short* G = (unsigned short*)(ws + 73472);   // 8320*256 bf16 -> 4333312
    float*    pP      = (float*)(ws + 4333312);  // 65*8320 f32 -> 6496512
    float*    pN      = (float*)(ws + 6496512);  // 65*8320 f32 -> 8659712

    hipMemsetAsync(ws, 0, 7296, stream);   // zero S_, Wsum, hist, maxb, lossacc

    kprep<<<1, 256, 0, stream>>>(labels, wbuf, labs, hist);
    kaccum<<<128, 256, 0, stream>>>(feats, labels, wbuf, S_, Wsum);
    kproto<<<1, 256, 0, stream>>>(S_, Wsum, hist, protos, moms, G);
    knorm<<<2048, 256, 0, stream>>>(feats, G);
    kmain<<<NBLK, 256, 0, stream>>>(G, labs, pP, pN, maxb);
    kreduce<<<33, 256, 0, stream>>>(pP, pN, maxb, hist, labs, lossacc);
    kfin<<<1, 64, 0, stream>>>(lossacc, out);
}

// Round 3
// 134.061 us; speedup vs baseline: 2.3745x; 1.5990x over previous
//
#include <hip/hip_runtime.h>
#include <stdint.h>

// ---------------- problem constants ----------------
#define B    8192
#define D    256
#define C    7
#define NTOT 8199          // B + C
#define NP   8320          // 65 * 128 (padded rows)
#define NTILE 65
#define NBLK 2145          // 65*66/2 triangular
#define BETAC 0.005f       // 0.5*(1-GAMMA)
#define L2GAMMA (-0.0144995696951151f)  // log2(0.99)

using short8 = __attribute__((ext_vector_type(8))) short;
using f32x4  = __attribute__((ext_vector_type(4))) float;

// bf16 round-to-nearest-even from f32
__device__ __forceinline__ unsigned short f2bf(float x) {
    unsigned u = __float_as_uint(x);
    unsigned r = (u + 0x7fffu + ((u >> 16) & 1u)) >> 16;
    return (unsigned short)r;
}

__device__ __forceinline__ void async16(const void* src, void* dst) {
    __builtin_amdgcn_global_load_lds(
        (const __attribute__((address_space(1))) void*)src,
        (__attribute__((address_space(3))) void*)dst, 16, 0, 0);
}

// score formula: ((1+sim)*0.5 + 1e-8) * 12.5 = sim*6.25 + (6.25 + 1.25e-7)
__device__ __forceinline__ float score_of(float sim) {
    return fmaf(sim, 6.25f, 6.25f + 1.25e-7f);
}

#define WAITVM(N) asm volatile("s_waitcnt vmcnt(" #N ")" ::: "memory")
#define BARRIER() do { __builtin_amdgcn_s_barrier(); asm volatile("" ::: "memory"); } while(0)

// ---------------- kernel 1: ranks -> weights, labs_ext, histogram ----------------
__global__ void kprep(const int* __restrict__ labels, float* __restrict__ wbuf,
                      int* __restrict__ labs_ext, int* __restrict__ hist) {
    __shared__ int cnt[256 * 8];
    __shared__ int tot[8];
    int t = threadIdx.x;
    int lane = t & 63, w = t >> 6;
    #pragma unroll
    for (int c = 0; c < 8; ++c) cnt[t * 8 + c] = 0;
    __syncthreads();
    // pass 1: per-chunk class counts (thread t owns labels 32t..32t+31)
    for (int k = 0; k < 32; ++k) {
        int c = labels[t * 32 + k];
        cnt[t * 8 + c]++;
    }
    __syncthreads();
    // wave-parallel exclusive scan per class over the 256 chunks
    for (int c = w; c < C; c += 4) {
        int v[4], partial = 0;
        #pragma unroll
        for (int k = 0; k < 4; ++k) { v[k] = cnt[(lane * 4 + k) * 8 + c]; partial += v[k]; }
        int inc = partial;
        #pragma unroll
        for (int d = 1; d < 64; d <<= 1) {
            int y = __shfl_up(inc, d);
            if (lane >= d) inc += y;
        }
        int run = inc - partial;          // exclusive base for this lane's 4 chunks
        #pragma unroll
        for (int k = 0; k < 4; ++k) { int tmp = v[k]; cnt[(lane * 4 + k) * 8 + c] = run; run += tmp; }
        if (lane == 63) { tot[c] = inc; hist[c] = inc; }
    }
    __syncthreads();
    // pass 2: rank -> weight = gamma^(n_c - rank)
    for (int k = 0; k < 32; ++k) {
        int idx = t * 32 + k;
        int c = labels[idx];
        int r = ++cnt[t * 8 + c];          // 1-based rank in batch order
        int kk = tot[c] - r;
        wbuf[idx] = exp2f((float)kk * L2GAMMA);
    }
    for (int i = t; i < NP; i += 256)
        labs_ext[i] = (i < B) ? labels[i] : ((i < NTOT) ? (i - B) : -1);
}

// ---------------- kernel 2: S[c][d] = sum w_i f_i[d] (register accum) ----------------
__global__ void kaccum(const float* __restrict__ feats, const int* __restrict__ labels,
                       const float* __restrict__ wbuf, float* __restrict__ S) {
    int t = threadIdx.x;
    int base = blockIdx.x * 32;
    float a[7] = {0.f, 0.f, 0.f, 0.f, 0.f, 0.f, 0.f};
    for (int r = 0; r < 32; ++r) {
        int row = base + r;
        int c = labels[row];
        float wf = wbuf[row] * feats[(size_t)row * 256 + t];
        #pragma unroll
        for (int cc = 0; cc < 7; ++cc)
            a[cc] += (cc == c) ? wf : 0.f;
    }
    #pragma unroll
    for (int cc = 0; cc < 7; ++cc)
        atomicAdd(&S[cc * 256 + t], a[cc]);
}

// ---------------- kernel 3: target build + Householder QR + proto G rows ----------------
__global__ void kproto(const float* __restrict__ S, const int* __restrict__ hist,
                       const float* __restrict__ protos, const float* __restrict__ moms,
                       unsigned short* __restrict__ G) {
    __shared__ float A[256 * 8];
    __shared__ float V[256 * 8];
    __shared__ float vvs[8];
    __shared__ float bcast[8];
    int t = threadIdx.x;
    int lane = t & 63, w = t >> 6;
    #pragma unroll
    for (int c = 0; c < C; ++c) {
        float p = protos[c * 256 + t];
        float m0 = moms[c * 256 + t];
        float gn = exp2f((float)hist[c] * L2GAMMA);     // gamma^{n_c}
        // Wsum closed form: beta*Wsum = 0.5*(1-gn)
        float mf = gn * m0 + BETAC * S[c * 256 + t] - 0.5f * (1.f - gn) * p;
        A[t * 8 + c] = p + mf;
        V[t * 8 + c] = 0.f;
    }
    __syncthreads();
    for (int j = 0; j < C; ++j) {
        if (w == 0) {
            float s = 0.f;
            for (int i = lane; i < 256; i += 64) {
                float a = (i >= j) ? A[i * 8 + j] : 0.f;
                s += a * a;
            }
            #pragma unroll
            for (int off = 32; off; off >>= 1) s += __shfl_xor(s, off);
            if (lane == 0) {
                float norm = sqrtf(s);
                float alpha = A[j * 8 + j];
                float beta = (alpha >= 0.f) ? -norm : norm;
                float vv = 2.f * beta * (beta - alpha);
                bcast[0] = alpha; bcast[1] = beta;
                bcast[2] = (vv > 0.f) ? 1.f : 0.f;
                vvs[j] = (vv > 0.f) ? vv : 1.f;
            }
        }
        __syncthreads();
        float alpha = bcast[0], valid = bcast[2];
        float beta = bcast[1];
        float vi = 0.f;
        if (valid != 0.f) {
            if (t == j) vi = alpha - beta;
            else if (t > j) vi = A[t * 8 + j];
        }
        V[t * 8 + j] = vi;
        __syncthreads();
        float vvj = vvs[j];
        for (int k = j + 1 + w; k < C; k += 4) {
            float cp = 0.f;
            for (int i = lane; i < 256; i += 64) cp += V[i * 8 + j] * A[i * 8 + k];
            #pragma unroll
            for (int off = 32; off; off >>= 1) cp += __shfl_xor(cp, off);
            float scale = 2.f * cp / vvj;
            for (int i = lane; i < 256; i += 64) A[i * 8 + k] -= scale * V[i * 8 + j];
        }
        __syncthreads();
    }
    #pragma unroll
    for (int c = 0; c < C; ++c) A[t * 8 + c] = (t == c) ? 1.f : 0.f;
    __syncthreads();
    for (int j = C - 1; j >= 0; --j) {
        float vvj = vvs[j];
        for (int k = w; k < C; k += 4) {
            float cp = 0.f;
            for (int i = lane; i < 256; i += 64) cp += V[i * 8 + j] * A[i * 8 + k];
            #pragma unroll
            for (int off = 32; off; off >>= 1) cp += __shfl_xor(cp, off);
            float scale = 2.f * cp / vvj;
            for (int i = lane; i < 256; i += 64) A[i * 8 + k] -= scale * V[i * 8 + j];
        }
        __syncthreads();
    }
    for (int c = w; c < C; c += 4) {
        float s = 0.f;
        for (int i = lane; i < 256; i += 64) { float a = A[i * 8 + c]; s += a * a; }
        #pragma unroll
        for (int off = 32; off; off >>= 1) s += __shfl_xor(s, off);
        if (lane == 0) bcast[c] = 1.f / sqrtf(s);
    }
    __syncthreads();
    #pragma unroll
    for (int c = 0; c < C; ++c)
        G[(size_t)(B + c) * 256 + t] = f2bf(A[t * 8 + c] * bcast[c]);
    for (int i = NTOT * 256 + t; i < NP * 256; i += 256) G[i] = 0;
}

// ---------------- kernel 4: normalize features -> bf16 G rows 0..8191 ----------------
__global__ void knorm(const float* __restrict__ feats, unsigned short* __restrict__ G) {
    int w = threadIdx.x >> 6, lane = threadIdx.x & 63;
    int row = blockIdx.x * 4 + w;
    const float4 v = *(const float4*)(feats + (size_t)row * 256 + lane * 4);
    float s = v.x * v.x + v.y * v.y + v.z * v.z + v.w * v.w;
    #pragma unroll
    for (int off = 1; off < 64; off <<= 1) s += __shfl_xor(s, off);
    float rn = 1.f / sqrtf(s);
    ushort4 o;
    o.x = f2bf(v.x * rn); o.y = f2bf(v.y * rn);
    o.z = f2bf(v.z * rn); o.w = f2bf(v.w * rn);
    *(ushort4*)(G + (size_t)row * 256 + lane * 4) = o;
}

// ---------------- kernel 5: symmetric fused G G^T, double-buffered, no atomics ----------------
__global__ __launch_bounds__(256, 2) void kmain(const unsigned short* __restrict__ G,
                                                const int* __restrict__ labs,
                                                float* __restrict__ pP,
                                                float* __restrict__ pN) {
    __shared__ unsigned short A2[2][128][64];     // double-buffered K-tiles (16 KB each)
    __shared__ unsigned short B2[2][128][64];
    __shared__ int   labIJ[256];                  // labI | labJ
    __shared__ float rowP[2][128], rowN[2][128];  // cross-wc combine
    __shared__ float colP[2][128], colN[2][128];  // cross-wr combine

    int b = blockIdx.x;
    // triangular decode: pairs (it <= jt)
    int jt = (int)((sqrtf(8.f * (float)b + 1.f) - 1.f) * 0.5f);
    while ((jt * (jt + 1)) / 2 > b) --jt;
    while (((jt + 1) * (jt + 2)) / 2 <= b) ++jt;
    int it = b - (jt * (jt + 1)) / 2;

    int rowA = it * 128, rowB = jt * 128;
    int tid = threadIdx.x, lane = tid & 63, w = tid >> 6;
    int wr = w >> 1, wc = w & 1;

    const char* gb = (const char*)G;
    const char* lb = (const char*)labs;

    // stage one K-tile (BK=64) of A and B into buffer `buf`
#define STAGE(BUF, KS)                                                         \
    do {                                                                       \
        _Pragma("unroll")                                                      \
        for (int q = 0; q < 4; ++q) {                                          \
            int o = q * 4096 + w * 1024 + lane * 16;                           \
            int row = o >> 7, colb = o & 127;                                  \
            int sc = colb ^ ((row & 7) << 4);      /* inverse-swizzled SOURCE */\
            const char* sA = gb + (size_t)(rowA + row) * 512 + (KS) * 128 + sc;\
            const char* sB = gb + (size_t)(rowB + row) * 512 + (KS) * 128 + sc;\
            async16(sA, (char*)A2 + (BUF) * 16384 + q * 4096 + w * 1024);      \
            async16(sB, (char*)B2 + (BUF) * 16384 + q * 4096 + w * 1024);      \
        }                                                                      \
    } while (0)

    // label load first (completes with first WAITVM(8))
    {
        const char* src = (lane < 32) ? (lb + rowA * 4 + lane * 16)
                                      : (lb + rowB * 4 + (lane - 32) * 16);
        async16(src, (char*)labIJ);
    }
    STAGE(0, 0);
    STAGE(1, 1);

    f32x4 acc[4][4];
    #pragma unroll
    for (int m = 0; m < 4; ++m)
        #pragma unroll
        for (int n = 0; n < 4; ++n) acc[m][n] = 0.f;

#define KSTEP(BUF)                                                             \
    do {                                                                       \
        _Pragma("unroll")                                                      \
        for (int kk = 0; kk < 2; ++kk) {                                       \
            short8 af[4], bfr[4];                                              \
            _Pragma("unroll")                                                  \
            for (int m = 0; m < 4; ++m) {                                      \
                int r0 = wr * 64 + m * 16 + (lane & 15);                       \
                int cb = (kk * 64 + (lane >> 4) * 16) ^ ((r0 & 7) << 4);       \
                af[m] = *(const short8*)((const char*)A2 + (BUF) * 16384 + r0 * 128 + cb); \
            }                                                                  \
            _Pragma("unroll")                                                  \
            for (int n = 0; n < 4; ++n) {                                      \
                int r0 = wc * 64 + n * 16 + (lane & 15);                       \
                int cb = (kk * 64 + (lane >> 4) * 16) ^ ((r0 & 7) << 4);       \
                bfr[n] = *(const short8*)((const char*)B2 + (BUF) * 16384 + r0 * 128 + cb); \
            }                                                                  \
            __builtin_amdgcn_s_setprio(1);                                     \
            _Pragma("unroll")                                                  \
            for (int m = 0; m < 4; ++m)                                        \
                _Pragma("unroll")                                              \
                for (int n = 0; n < 4; ++n)                                    \
                    acc[m][n] = __builtin_amdgcn_mfma_f32_16x16x32_bf16(af[m], bfr[n], acc[m][n], 0, 0, 0); \
            __builtin_amdgcn_s_setprio(0);                                     \
        }                                                                      \
    } while (0)

    WAITVM(8); BARRIER();
    KSTEP(0);
    BARRIER(); STAGE(0, 2); WAITVM(8); BARRIER();
    KSTEP(1);
    BARRIER(); STAGE(1, 3); WAITVM(8); BARRIER();
    KSTEP(0);
    WAITVM(0); BARRIER();
    KSTEP(1);
#undef KSTEP
#undef STAGE

    // ---- fused epilogue: C/D layout col=lane&15, row=(lane>>4)*4+reg
    int g4 = lane >> 4, q15 = lane & 15;
    const int* labI = labIJ;
    const int* labJ = labIJ + 128;
    int ljv[4];
    #pragma unroll
    for (int n = 0; n < 4; ++n) ljv[n] = labJ[wc * 64 + n * 16 + q15];
    float cs[4] = {0.f, 0.f, 0.f, 0.f}, cn[4] = {0.f, 0.f, 0.f, 0.f};
    #pragma unroll
    for (int m = 0; m < 4; ++m) {
        #pragma unroll
        for (int r = 0; r < 4; ++r) {
            int il = wr * 64 + m * 16 + g4 * 4 + r;
            int i = rowA + il;
            int li = labI[il];
            float ps = 0.f, ns = 0.f;
            #pragma unroll
            for (int n = 0; n < 4; ++n) {
                int j = rowB + wc * 64 + n * 16 + q15;
                float sim = acc[m][n][r];
                bool valid = (i < NTOT) && (j < NTOT) && (i != j);
                float s = score_of(sim);
                float e = __expf(s);
                if (valid) {
                    if (li == ljv[n]) { ps += s; cs[n] += s; }
                    else              { ns += e; cn[n] += e; }
                }
            }
            #pragma unroll
            for (int off = 1; off < 16; off <<= 1) {
                ps += __shfl_xor(ps, off);
                ns += __shfl_xor(ns, off);
            }
            if (q15 == 0) { rowP[wc][il] = ps; rowN[wc][il] = ns; }
        }
    }
    // col-side: reduce over g4 groups (same q15, different rows)
    #pragma unroll
    for (int n = 0; n < 4; ++n) {
        float a = cs[n], bb = cn[n];
        a += __shfl_xor(a, 16); a += __shfl_xor(a, 32);
        bb += __shfl_xor(bb, 16); bb += __shfl_xor(bb, 32);
        if (g4 == 0) {
            colP[wr][wc * 64 + n * 16 + q15] = a;
            colN[wr][wc * 64 + n * 16 + q15] = bb;
        }
    }

    __syncthreads();
    if (tid < 128) {
        pP[(size_t)jt * NP + rowA + tid] = rowP[0][tid] + rowP[1][tid];
        pN[(size_t)jt * NP + rowA + tid] = rowN[0][tid] + rowN[1][tid];
        if (it != jt) {
            pP[(size_t)it * NP + rowB + tid] = colP[0][tid] + colP[1][tid];
            pN[(size_t)it * NP + rowB + tid] = colN[0][tid] + colN[1][tid];
        }
    }
}

// ---------------- kernel 6: reduce partials -> per-row loss -> masked-mean pieces ----------------
__global__ void kreduce(const float* __restrict__ pP, const float* __restrict__ pN,
                        const int* __restrict__ hist, const int* __restrict__ labs,
                        float* __restrict__ lossacc) {
    int i = blockIdx.x * 256 + threadIdx.x;
    float lsum = 0.f, lcnt = 0.f;
    if (i < NTOT) {
        float sp = 0.f, sn = 0.f;
        #pragma unroll 5
        for (int c = 0; c < NTILE; ++c) {
            sp += pP[(size_t)c * NP + i];
            sn += pN[(size_t)c * NP + i];
        }
        // M = 0 shift: differs from reference's global-max shift by <=~1e-7
        float cnt = (float)hist[labs[i]];
        float pos = sp / (cnt + 1e-8f);
        float neg = logf(sn + 1e-8f);
        float loss = neg - pos;
        if (loss > 0.f) { lsum = loss; lcnt = 1.f; }
    }
    #pragma unroll
    for (int off = 1; off < 64; off <<= 1) {
        lsum += __shfl_xor(lsum, off);
        lcnt += __shfl_xor(lcnt, off);
    }
    __shared__ float s1[4], s2[4];
    int lane = threadIdx.x & 63, w = threadIdx.x >> 6;
    if (lane == 0) { s1[w] = lsum; s2[w] = lcnt; }
    __syncthreads();
    if (threadIdx.x == 0) {
        atomicAdd(&lossacc[0], s1[0] + s1[1] + s1[2] + s1[3]);
        atomicAdd(&lossacc[1], s2[0] + s2[1] + s2[2] + s2[3]);
    }
}

__global__ void kfin(const float* __restrict__ lossacc, float* __restrict__ out) {
    if (threadIdx.x == 0) {
        float a = lossacc[0], c = lossacc[1];
        out[0] = (c > 0.f) ? a / fmaxf(c, 1.f) : 0.f;
    }
}

// ---------------- launcher ----------------
extern "C" void kernel_launch(void* const* d_in, const int* in_sizes, int n_in,
                              void* d_out, int out_size, void* d_ws, size_t ws_size,
                              hipStream_t stream) {
    const float* feats  = (const float*)d_in[0];
    const int*   labels = (const int*)d_in[1];
    const float* protos = (const float*)d_in[2];
    const float* moms   = (const float*)d_in[3];
    float* out = (float*)d_out;

    char* ws = (char*)d_ws;
    float*    S_      = (float*)(ws + 0);        // 1792 f32
    int*      hist    = (int*)  (ws + 7168);     // 8 int
    float*    lossacc = (float*)(ws + 7200);     // 2 f32
    float*    wbuf    = (float*)(ws + 7296);     // 8192 f32 -> 40064
    int*      labs    = (int*)  (ws + 40064);    // 8320 int -> 73344
    unsigned short* G = (unsigned short*)(ws + 73472);   // 8320*256 bf16 -> 4333312
    float*    pP      = (float*)(ws + 4333312);  // 65*8320 f32 -> 6496512
    float*    pN      = (float*)(ws + 6496512);  // 65*8320 f32 -> 8659712

    hipMemsetAsync(ws, 0, 7296, stream);   // zero S_, hist, lossacc

    kprep<<<1, 256, 0, stream>>>(labels, wbuf, labs, hist);
    kaccum<<<256, 256, 0, stream>>>(feats, labels, wbuf, S_);
    kproto<<<1, 256, 0, stream>>>(S_, hist, protos, moms, G);
    knorm<<<2048, 256, 0, stream>>>(feats, G);
    kmain<<<NBLK, 256, 0, stream>>>(G, labs, pP, pN);
    kreduce<<<33, 256, 0, stream>>>(pP, pN, hist, labs, lossacc);
    kfin<<<1, 64, 0, stream>>>(lossacc, out);
}

// Round 5
// 123.559 us; speedup vs baseline: 2.5763x; 1.0850x over previous
//
#include <hip/hip_runtime.h>
#include <stdint.h>

// ---------------- problem constants ----------------
#define B    8192
#define D    256
#define C    7
#define NTOT 8199          // B + C
#define NPAD 8448          // 33 * 256 (padded rows)
#define NT   33            // 256-row tiles
#define NBLK 561           // 33*34/2 triangular
#define BETAC 0.005f       // 0.5*(1-GAMMA)
#define L2GAMMA (-0.0144995696951151f)  // log2(0.99)

using short8 = __attribute__((ext_vector_type(8))) short;
using f32x4  = __attribute__((ext_vector_type(4))) float;

// bf16 round-to-nearest-even from f32
__device__ __forceinline__ unsigned short f2bf(float x) {
    unsigned u = __float_as_uint(x);
    unsigned r = (u + 0x7fffu + ((u >> 16) & 1u)) >> 16;
    return (unsigned short)r;
}

__device__ __forceinline__ void async16(const void* src, void* dst) {
    __builtin_amdgcn_global_load_lds(
        (const __attribute__((address_space(1))) void*)src,
        (__attribute__((address_space(3))) void*)dst, 16, 0, 0);
}

// score formula: ((1+sim)*0.5 + 1e-8) * 12.5 = sim*6.25 + (6.25 + 1.25e-7)
__device__ __forceinline__ float score_of(float sim) {
    return fmaf(sim, 6.25f, 6.25f + 1.25e-7f);
}

#define WAITVM(N) asm volatile("s_waitcnt vmcnt(" #N ")" ::: "memory")
#define BARRIER() do { __builtin_amdgcn_s_barrier(); asm volatile("" ::: "memory"); } while(0)

// ---------------- kernel 1: zero accums, ranks -> weights, labs_ext, histogram ----------------
__global__ void kprep(const int* __restrict__ labels, float* __restrict__ wbuf,
                      int* __restrict__ labs_ext, int* __restrict__ hist,
                      float* __restrict__ S, float* __restrict__ lossacc,
                      unsigned* __restrict__ ticket) {
    __shared__ int cnt[256 * 8];
    __shared__ int tot[8];
    int t = threadIdx.x;
    int lane = t & 63, w = t >> 6;
    // zero this call's accumulators (replaces hipMemsetAsync)
    for (int i = t; i < C * 256; i += 256) S[i] = 0.f;
    if (t == 0) { lossacc[0] = 0.f; lossacc[1] = 0.f; *ticket = 0u; }
    // load this thread's 32 labels once (int4 x8), reused in both passes
    int lab[32];
    #pragma unroll
    for (int q = 0; q < 8; ++q) {
        int4 v = *(const int4*)(labels + t * 32 + q * 4);
        lab[q * 4 + 0] = v.x; lab[q * 4 + 1] = v.y;
        lab[q * 4 + 2] = v.z; lab[q * 4 + 3] = v.w;
    }
    // pass 1: per-chunk class counts in registers (no LDS RMW conflicts)
    int myc[8] = {0, 0, 0, 0, 0, 0, 0, 0};
    #pragma unroll
    for (int k = 0; k < 32; ++k) {
        #pragma unroll
        for (int cc = 0; cc < 7; ++cc) myc[cc] += (lab[k] == cc) ? 1 : 0;
    }
    #pragma unroll
    for (int cc = 0; cc < 8; ++cc) cnt[t * 8 + cc] = myc[cc];
    __syncthreads();
    // wave-parallel exclusive scan per class over the 256 chunks
    for (int c = w; c < C; c += 4) {
        int v[4], partial = 0;
        #pragma unroll
        for (int k = 0; k < 4; ++k) { v[k] = cnt[(lane * 4 + k) * 8 + c]; partial += v[k]; }
        int inc = partial;
        #pragma unroll
        for (int d = 1; d < 64; d <<= 1) {
            int y = __shfl_up(inc, d);
            if (lane >= d) inc += y;
        }
        int run = inc - partial;          // exclusive base for this lane's 4 chunks
        #pragma unroll
        for (int k = 0; k < 4; ++k) { int tmp = v[k]; cnt[(lane * 4 + k) * 8 + c] = run; run += tmp; }
        if (lane == 63) { tot[c] = inc; hist[c] = inc; }
    }
    __syncthreads();
    // pass 2: rank -> weight = gamma^(n_c - rank)
    #pragma unroll 4
    for (int k = 0; k < 32; ++k) {
        int idx = t * 32 + k;
        int c = lab[k];
        int r = ++cnt[t * 8 + c];          // 1-based rank in batch order
        int kk = tot[c] - r;
        wbuf[idx] = exp2f((float)kk * L2GAMMA);
    }
    for (int i = t; i < NPAD; i += 256)
        labs_ext[i] = (i < B) ? labels[i] : ((i < NTOT) ? (i - B) : -1);
}

// ---------------- kernel 2: fused normalize->G + weighted class sums S ----------------
__global__ void kaccnorm(const float* __restrict__ feats, const int* __restrict__ labels,
                         const float* __restrict__ wbuf, float* __restrict__ S,
                         unsigned short* __restrict__ G) {
    __shared__ float sacc[4][7][256];
    int tid = threadIdx.x, lane = tid & 63, wv = tid >> 6;
    float acc7[7][4] = {};
    int base = blockIdx.x * 32 + wv * 8;
    for (int k = 0; k < 8; ++k) {
        int row = base + k;
        const float4 v = *(const float4*)(feats + (size_t)row * 256 + lane * 4);
        float ss = v.x * v.x + v.y * v.y + v.z * v.z + v.w * v.w;
        #pragma unroll
        for (int off = 1; off < 64; off <<= 1) ss += __shfl_xor(ss, off);
        float rn = 1.f / sqrtf(ss);
        ushort4 o;
        o.x = f2bf(v.x * rn); o.y = f2bf(v.y * rn);
        o.z = f2bf(v.z * rn); o.w = f2bf(v.w * rn);
        *(ushort4*)(G + (size_t)row * 256 + lane * 4) = o;
        int c = labels[row];               // wave-uniform
        float wgt = wbuf[row];
        float w0 = v.x * wgt, w1 = v.y * wgt, w2 = v.z * wgt, w3 = v.w * wgt;
        #pragma unroll
        for (int cc = 0; cc < 7; ++cc)
            if (c == cc) { acc7[cc][0] += w0; acc7[cc][1] += w1; acc7[cc][2] += w2; acc7[cc][3] += w3; }
    }
    #pragma unroll
    for (int cc = 0; cc < 7; ++cc) {
        #pragma unroll
        for (int jj = 0; jj < 4; ++jj)
            sacc[wv][cc][lane * 4 + jj] = acc7[cc][jj];
    }
    __syncthreads();
    #pragma unroll
    for (int cc = 0; cc < 7; ++cc) {
        float s = sacc[0][cc][tid] + sacc[1][cc][tid] + sacc[2][cc][tid] + sacc[3][cc][tid];
        atomicAdd(&S[cc * 256 + tid], s);
    }
    // zero the pad G rows (8199..8447), one row per block
    if (blockIdx.x < NPAD - NTOT)
        G[(size_t)(NTOT + blockIdx.x) * 256 + tid] = 0;
}

// ---------------- kernel 3: target build + Householder QR + proto G rows ----------------
__global__ void kproto(const float* __restrict__ S, const int* __restrict__ hist,
                       const float* __restrict__ protos, const float* __restrict__ moms,
                       unsigned short* __restrict__ G) {
    __shared__ float A[256 * 8];
    __shared__ float V[256 * 8];
    __shared__ float vvs[8];
    __shared__ float bcast[8];
    int t = threadIdx.x;
    int lane = t & 63, w = t >> 6;
    #pragma unroll
    for (int c = 0; c < C; ++c) {
        float p = protos[c * 256 + t];
        float m0 = moms[c * 256 + t];
        float gn = exp2f((float)hist[c] * L2GAMMA);     // gamma^{n_c}
        // Wsum closed form: beta*Wsum = 0.5*(1-gn)
        float mf = gn * m0 + BETAC * S[c * 256 + t] - 0.5f * (1.f - gn) * p;
        A[t * 8 + c] = p + mf;
        V[t * 8 + c] = 0.f;
    }
    __syncthreads();
    for (int j = 0; j < C; ++j) {
        if (w == 0) {
            float s = 0.f;
            for (int i = lane; i < 256; i += 64) {
                float a = (i >= j) ? A[i * 8 + j] : 0.f;
                s += a * a;
            }
            #pragma unroll
            for (int off = 32; off; off >>= 1) s += __shfl_xor(s, off);
            if (lane == 0) {
                float norm = sqrtf(s);
                float alpha = A[j * 8 + j];
                float beta = (alpha >= 0.f) ? -norm : norm;
                float vv = 2.f * beta * (beta - alpha);
                bcast[0] = alpha; bcast[1] = beta;
                bcast[2] = (vv > 0.f) ? 1.f : 0.f;
                vvs[j] = (vv > 0.f) ? vv : 1.f;
            }
        }
        __syncthreads();
        float alpha = bcast[0], valid = bcast[2];
        float beta = bcast[1];
        float vi = 0.f;
        if (valid != 0.f) {
            if (t == j) vi = alpha - beta;
            else if (t > j) vi = A[t * 8 + j];
        }
        V[t * 8 + j] = vi;
        __syncthreads();
        float vvj = vvs[j];
        for (int k = j + 1 + w; k < C; k += 4) {
            float cp = 0.f;
            for (int i = lane; i < 256; i += 64) cp += V[i * 8 + j] * A[i * 8 + k];
            #pragma unroll
            for (int off = 32; off; off >>= 1) cp += __shfl_xor(cp, off);
            float scale = 2.f * cp / vvj;
            for (int i = lane; i < 256; i += 64) A[i * 8 + k] -= scale * V[i * 8 + j];
        }
        __syncthreads();
    }
    #pragma unroll
    for (int c = 0; c < C; ++c) A[t * 8 + c] = (t == c) ? 1.f : 0.f;
    __syncthreads();
    for (int j = C - 1; j >= 0; --j) {
        float vvj = vvs[j];
        for (int k = w; k < C; k += 4) {
            float cp = 0.f;
            for (int i = lane; i < 256; i += 64) cp += V[i * 8 + j] * A[i * 8 + k];
            #pragma unroll
            for (int off = 32; off; off >>= 1) cp += __shfl_xor(cp, off);
            float scale = 2.f * cp / vvj;
            for (int i = lane; i < 256; i += 64) A[i * 8 + k] -= scale * V[i * 8 + j];
        }
        __syncthreads();
    }
    for (int c = w; c < C; c += 4) {
        float s = 0.f;
        for (int i = lane; i < 256; i += 64) { float a = A[i * 8 + c]; s += a * a; }
        #pragma unroll
        for (int off = 32; off; off >>= 1) s += __shfl_xor(s, off);
        if (lane == 0) bcast[c] = 1.f / sqrtf(s);
    }
    __syncthreads();
    #pragma unroll
    for (int c = 0; c < C; ++c)
        G[(size_t)(B + c) * 256 + t] = f2bf(A[t * 8 + c] * bcast[c]);
}

// ---------------- kernel 4: 256x256 symmetric fused G G^T ----------------
__global__ __launch_bounds__(512, 2) void kmain(const unsigned short* __restrict__ G,
                                                const int* __restrict__ labs,
                                                float* __restrict__ pP,
                                                float* __restrict__ pN) {
    __shared__ unsigned short A2[2][256][64];     // double-buffered K-tiles (32 KB each)
    __shared__ unsigned short B2[2][256][64];
    __shared__ float rowP[4][256], rowN[4][256];  // cross-wc combine
    __shared__ float colP[2][256], colN[2][256];  // cross-wr combine

    // bijective XCD swizzle (561 = 8*70 + 1)
    int b0 = blockIdx.x;
    int xcd = b0 & 7, pos = b0 >> 3;
    int b = (xcd == 0) ? pos : (71 + (xcd - 1) * 70 + pos);

    // triangular decode: pairs (it <= jt)
    int jt = (int)((sqrtf(8.f * (float)b + 1.f) - 1.f) * 0.5f);
    while ((jt * (jt + 1)) / 2 > b) --jt;
    while (((jt + 1) * (jt + 2)) / 2 <= b) ++jt;
    int it = b - (jt * (jt + 1)) / 2;

    int rowA = it * 256, rowB = jt * 256;
    int tid = threadIdx.x, lane = tid & 63, w8 = tid >> 6;
    int wr = w8 >> 2, wc = w8 & 3;                // 2x4 wave grid

    const char* gb = (const char*)G;

    // stage one K-tile (BK=64) of A and B (256 rows each) into buffer BUF
#define STAGE(BUF, KS)                                                         \
    do {                                                                       \
        _Pragma("unroll")                                                      \
        for (int q = 0; q < 4; ++q) {                                          \
            int o = q * 8192 + w8 * 1024 + lane * 16;                          \
            int row = o >> 7, colb = o & 127;                                  \
            int sc = colb ^ ((row & 7) << 4);      /* inverse-swizzled SOURCE */\
            const char* sA = gb + (size_t)(rowA + row) * 512 + (KS) * 128 + sc;\
            const char* sB = gb + (size_t)(rowB + row) * 512 + (KS) * 128 + sc;\
            async16(sA, (char*)A2 + (BUF) * 65536 + q * 8192 + w8 * 1024);     \
            async16(sB, (char*)B2 + (BUF) * 65536 + q * 8192 + w8 * 1024);     \
        }                                                                      \
    } while (0)

    STAGE(0, 0);
    STAGE(1, 1);

    f32x4 acc[8][4];
    #pragma unroll
    for (int m = 0; m < 8; ++m)
        #pragma unroll
        for (int n = 0; n < 4; ++n) acc[m][n] = 0.f;

#define KSTEP(BUF)                                                             \
    do {                                                                       \
        _Pragma("unroll")                                                      \
        for (int kk = 0; kk < 2; ++kk) {                                       \
            short8 af[8], bfr[4];                                              \
            _Pragma("unroll")                                                  \
            for (int m = 0; m < 8; ++m) {                                      \
                int r0 = wr * 128 + m * 16 + (lane & 15);                      \
                int cb = (kk * 64 + (lane >> 4) * 16) ^ ((r0 & 7) << 4);       \
                af[m] = *(const short8*)((const char*)A2 + (BUF) * 65536 + r0 * 128 + cb); \
            }                                                                  \
            _Pragma("unroll")                                                  \
            for (int n = 0; n < 4; ++n) {                                      \
                int r0 = wc * 64 + n * 16 + (lane & 15);                       \
                int cb = (kk * 64 + (lane >> 4) * 16) ^ ((r0 & 7) << 4);       \
                bfr[n] = *(const short8*)((const char*)B2 + (BUF) * 65536 + r0 * 128 + cb); \
            }                                                                  \
            __builtin_amdgcn_s_setprio(1);                                     \
            _Pragma("unroll")                                                  \
            for (int m = 0; m < 8; ++m)                                        \
                _Pragma("unroll")                                              \
                for (int n = 0; n < 4; ++n)                                    \
                    acc[m][n] = __builtin_amdgcn_mfma_f32_16x16x32_bf16(af[m], bfr[n], acc[m][n], 0, 0, 0); \
            __builtin_amdgcn_s_setprio(0);                                     \
        }                                                                      \
    } while (0)

    WAITVM(8); BARRIER();
    KSTEP(0);
    BARRIER(); STAGE(0, 2); WAITVM(8); BARRIER();
    KSTEP(1);
    BARRIER(); STAGE(1, 3); WAITVM(8); BARRIER();
    KSTEP(0);
    WAITVM(0); BARRIER();
    KSTEP(1);
#undef KSTEP
#undef STAGE

    // ---- fused epilogue: C/D layout col=lane&15, row=(lane>>4)*4+reg
    // labels read DIRECTLY from global (L2-hot) — no LDS staging.
    int g4 = lane >> 4, q15 = lane & 15;
    int ljv[4];
    #pragma unroll
    for (int n = 0; n < 4; ++n) ljv[n] = labs[rowB + wc * 64 + n * 16 + q15];
    float cs[4] = {0.f, 0.f, 0.f, 0.f}, cn[4] = {0.f, 0.f, 0.f, 0.f};
    bool fastpath = (it != jt) && (jt != NT - 1);

#define EPI(VALIDEXPR)                                                         \
    _Pragma("unroll")                                                          \
    for (int m = 0; m < 8; ++m) {                                              \
        int4 lrow = *(const int4*)(labs + rowA + wr * 128 + m * 16 + g4 * 4);  \
        _Pragma("unroll")                                                      \
        for (int r = 0; r < 4; ++r) {                                          \
            int il = wr * 128 + m * 16 + g4 * 4 + r;                           \
            int i = rowA + il; (void)i;                                        \
            int li = ((const int*)&lrow)[r];                                   \
            float ps = 0.f, ns = 0.f;                                          \
            _Pragma("unroll")                                                  \
            for (int n = 0; n < 4; ++n) {                                      \
                int j = rowB + wc * 64 + n * 16 + q15; (void)j;                \
                float sim = acc[m][n][r];                                      \
                float s = score_of(sim);                                       \
                float e = __expf(s);                                           \
                if (VALIDEXPR) {                                               \
                    if (li == ljv[n]) { ps += s; cs[n] += s; }                 \
                    else              { ns += e; cn[n] += e; }                 \
                }                                                              \
            }                                                                  \
            _Pragma("unroll")                                                  \
            for (int off = 1; off < 16; off <<= 1) {                           \
                ps += __shfl_xor(ps, off);                                     \
                ns += __shfl_xor(ns, off);                                     \
            }                                                                  \
            if (q15 == 0) { rowP[wc][il] = ps; rowN[wc][il] = ns; }            \
        }                                                                      \
    }

    if (fastpath) { EPI(true); }
    else          { EPI(i < NTOT && j < NTOT && i != j); }
#undef EPI

    // col-side: reduce over g4 groups (same q15-column, different rows)
    #pragma unroll
    for (int n = 0; n < 4; ++n) {
        float a = cs[n], bb = cn[n];
        a += __shfl_xor(a, 16); a += __shfl_xor(a, 32);
        bb += __shfl_xor(bb, 16); bb += __shfl_xor(bb, 32);
        if (g4 == 0) {
            colP[wr][wc * 64 + n * 16 + q15] = a;
            colN[wr][wc * 64 + n * 16 + q15] = bb;
        }
    }

    __syncthreads();
    if (tid < 256) {
        float sp = rowP[0][tid] + rowP[1][tid] + rowP[2][tid] + rowP[3][tid];
        float sn = rowN[0][tid] + rowN[1][tid] + rowN[2][tid] + rowN[3][tid];
        pP[(size_t)jt * NPAD + rowA + tid] = sp;
        pN[(size_t)jt * NPAD + rowA + tid] = sn;
    } else if (it != jt) {
        int tt = tid - 256;
        pP[(size_t)it * NPAD + rowB + tt] = colP[0][tt] + colP[1][tt];
        pN[(size_t)it * NPAD + rowB + tt] = colN[0][tt] + colN[1][tt];
    }
}

// ---------------- kernel 5: reduce partials -> loss, ticket finalize ----------------
__global__ void kreduce(const float* __restrict__ pP, const float* __restrict__ pN,
                        const int* __restrict__ hist, const int* __restrict__ labs,
                        float* __restrict__ lossacc, unsigned* __restrict__ ticket,
                        float* __restrict__ out) {
    int i = blockIdx.x * 256 + threadIdx.x;
    float lsum = 0.f, lcnt = 0.f;
    if (i < NTOT) {
        float sp = 0.f, sn = 0.f;
        #pragma unroll 3
        for (int c = 0; c < NT; ++c) {
            sp += pP[(size_t)c * NPAD + i];
            sn += pN[(size_t)c * NPAD + i];
        }
        // M = 0 shift: differs from reference's global-max shift by <=~1e-7
        float cnt = (float)hist[labs[i]];
        float pos = sp / (cnt + 1e-8f);
        float neg = logf(sn + 1e-8f);
        float loss = neg - pos;
        if (loss > 0.f) { lsum = loss; lcnt = 1.f; }
    }
    #pragma unroll
    for (int off = 1; off < 64; off <<= 1) {
        lsum += __shfl_xor(lsum, off);
        lcnt += __shfl_xor(lcnt, off);
    }
    __shared__ float s1[4], s2[4];
    int lane = threadIdx.x & 63, w = threadIdx.x >> 6;
    if (lane == 0) { s1[w] = lsum; s2[w] = lcnt; }
    __syncthreads();
    if (threadIdx.x == 0) {
        atomicAdd(&lossacc[0], s1[0] + s1[1] + s1[2] + s1[3]);
        atomicAdd(&lossacc[1], s2[0] + s2[1] + s2[2] + s2[3]);
        __threadfence();
        unsigned tk = atomicAdd(ticket, 1u);
        if (tk == 32) {   // last of 33 blocks: all adds visible
            float a = atomicAdd(&lossacc[0], 0.f);
            float c2 = atomicAdd(&lossacc[1], 0.f);
            out[0] = (c2 > 0.f) ? a / fmaxf(c2, 1.f) : 0.f;
        }
    }
}

// ---------------- launcher ----------------
extern "C" void kernel_launch(void* const* d_in, const int* in_sizes, int n_in,
                              void* d_out, int out_size, void* d_ws, size_t ws_size,
                              hipStream_t stream) {
    const float* feats  = (const float*)d_in[0];
    const int*   labels = (const int*)d_in[1];
    const float* protos = (const float*)d_in[2];
    const float* moms   = (const float*)d_in[3];
    float* out = (float*)d_out;

    char* ws = (char*)d_ws;
    float*    S_      = (float*)(ws + 0);        // 1792 f32 -> 7168
    int*      hist    = (int*)  (ws + 7168);     // 8 int    -> 7200
    float*    lossacc = (float*)(ws + 7200);     // 2 f32    -> 7208
    unsigned* ticket  = (unsigned*)(ws + 7208);  // 1 u32    -> 7212
    float*    wbuf    = (float*)(ws + 7296);     // 8192 f32 -> 40064
    int*      labs    = (int*)  (ws + 40064);    // 8448 int -> 73856
    unsigned short* G = (unsigned short*)(ws + 73856);   // 8448*256 bf16 -> 4399232
    float*    pP      = (float*)(ws + 4399232);  // 33*8448 f32 -> 5514368
    float*    pN      = (float*)(ws + 5514368);  // 33*8448 f32 -> 6629504

    kprep<<<1, 256, 0, stream>>>(labels, wbuf, labs, hist, S_, lossacc, ticket);
    kaccnorm<<<256, 256, 0, stream>>>(feats, labels, wbuf, S_, G);
    kproto<<<1, 256, 0, stream>>>(S_, hist, protos, moms, G);
    kmain<<<NBLK, 512, 0, stream>>>(G, labs, pP, pN);
    kreduce<<<33, 256, 0, stream>>>(pP, pN, hist, labs, lossacc, ticket, out);
}